// Round 5
// baseline (4373.142 us; speedup 1.0000x reference)
//
#include <hip/hip_runtime.h>
#include <stdint.h>
#include <stddef.h>

typedef _Float16 half_t;
typedef __attribute__((ext_vector_type(8))) _Float16 f16x8;
typedef __attribute__((ext_vector_type(16))) float f32x16;
typedef unsigned long long u64;

#define TSEQ 512
#define NSTAGE 521            // 512 + 3*3 fill (cross-layer lag-3)
#define SLOT 32768            // halfs per h slot (32 b x 1024 h)
#define LSTRIDE ((size_t)513 * SLOT)

__device__ __forceinline__ float sigmoidf_(float x) { return 1.f / (1.f + __expf(-x)); }
__device__ __forceinline__ float tanhf_(float x) { return 1.f - 2.f / (__expf(2.f * x) + 1.f); }

// ---- pack weights into per-CU, per-wave MFMA B-fragment order, f32 -> f16 ----
// dest idx = ((((l*64+cu)*4+kq)*2+nt)*32+c)*64+lane, 8 halfs each (k = kq*512+c*16+(lane>>5)*8+j)
// n' = nt*32+(lane&31): gate g = n'>>4, hcol = n'&15, n_glob = g*1024+cu*16+hcol
// Layer 0 K-map: k<512 -> W0 row k (x); 512<=k<1024 -> zero; k>=1024 -> W0 row k-512 (h).
__global__ void wconv_pack(const float* __restrict__ W0, const float* __restrict__ Wl,
                           half_t* __restrict__ WTp) {
    int idx = blockIdx.x * 256 + threadIdx.x;  // 0 .. 2^22-1
    int lane = idx & 63, c = (idx >> 6) & 31, nt = (idx >> 11) & 1;
    int kq = (idx >> 12) & 3, cu = (idx >> 14) & 63, l = idx >> 20;
    int np = nt * 32 + (lane & 31);
    int n = (np >> 4) * 1024 + cu * 16 + (np & 15);
    int kbase = kq * 512 + c * 16 + (lane >> 5) * 8;
    half_t tmp[8];
#pragma unroll
    for (int j = 0; j < 8; ++j) {
        int k = kbase + j;
        float v;
        if (l == 0) {
            if (k < 512) v = W0[(size_t)k * 4096 + n];
            else if (k < 1024) v = 0.f;
            else v = W0[(size_t)(k - 512) * 4096 + n];
        } else {
            v = Wl[((size_t)(l - 1) * 2048 + k) * 4096 + n];
        }
        tmp[j] = (half_t)v;
    }
    *(int4*)(WTp + (size_t)idx * 8) = *(int4*)tmp;
}

// ---- x f32 [32 b][512 t][512 k] -> xb f16 [t][128 c][32 b][8 j], zeros for c>=64 ----
__global__ void xconv(const float* __restrict__ x, half_t* __restrict__ xb) {
    int idx = blockIdx.x * 256 + threadIdx.x;  // 0 .. 2^21-1
    int b = idx & 31, c = (idx >> 5) & 127, t = idx >> 12;
    half_t tmp[8];
#pragma unroll
    for (int j = 0; j < 8; ++j)
        tmp[j] = (c < 64) ? (half_t)x[((size_t)b * 512 + t) * 512 + c * 8 + j] : (half_t)0.f;
    *(int4*)(xb + (size_t)idx * 8) = *(int4*)tmp;
}

// ---- h0 f32 [l][32 b][1024] -> h_out[l] slot 0 blocked [c][b][j] ----
__global__ void hinit(const float* __restrict__ h0, half_t* __restrict__ hO) {
    int idx = blockIdx.x * 256 + threadIdx.x;  // 0..16383
    int b = idx & 31, c = (idx >> 5) & 127, l = idx >> 12;
    half_t tmp[8];
#pragma unroll
    for (int j = 0; j < 8; ++j) tmp[j] = (half_t)h0[(size_t)l * 32768 + b * 1024 + c * 8 + j];
    *(int4*)(hO + (size_t)l * LSTRIDE + (size_t)(c * 32 + b) * 8) = *(int4*)tmp;
}

__global__ void init_flags(int* f, int n) {
    int i = blockIdx.x * blockDim.x + threadIdx.x;
    if (i < n) f[i] = 0;
}

// ---- persistent pipelined LSTM: 256 WGs (1/CU) x 512 threads (8 waves) ----
// WG wg: layer l = wg>>6, cu = wg&63 owns h-cols [cu*16, cu*16+16) of layer l.
// Wave wid: kq = wid>>1 (K quarter of 512), nt = wid&1 (32-col half of the 64 z-cols).
// SPLIT-LAG schedule: stage s, layer l computes t = s - 3l.
//   intra-layer (h_l(t-1), slot t):   produced stage s-1  -> wait own-layer flags >= s (tight)
//   cross-layer (h_{l-1}(t), slot t+1): produced stage s-3 -> covered by the PREVIOUS stage's
//     cross-wait (flags_{l-1} >= s-2), so x-part A-fragments are prefetched BEFORE polling;
//     this stage's cross-wait (>= s-1) has a full stage of slack (maintains the induction).
__global__ void __launch_bounds__(512, 2) lstm_pipe(
        const half_t* __restrict__ WTp, const half_t* __restrict__ xb,
        const float* __restrict__ b0, const float* __restrict__ bl,
        const float* __restrict__ c0, half_t* __restrict__ hO,
        int* __restrict__ flags) {
    __shared__ float zbuf[64 * 129];      // transposed: [col 64][row 128 + 1 pad]
    __shared__ half_t hbuf[512];

    const int tid = threadIdx.x;
    const int wg = blockIdx.x;
    const int l = wg >> 6, cu = wg & 63;
    const int lane = tid & 63, wid = tid >> 6;
    const int kq = wid >> 1, nt = wid & 1;
    const bool skipq = (l == 0 && kq == 1);  // zero-padded K region of layer 0

    // ---- B fragments: register-stationary for the whole sequence ----
    f16x8 bfr[32];
    {
        const half_t* wp = WTp + (size_t)(((wg * 4 + kq) * 2 + nt) * 32) * 512 + (size_t)lane * 8;
#pragma unroll
        for (int c = 0; c < 32; ++c) bfr[c] = *(const f16x8*)(wp + (size_t)c * 512);
    }

    // ---- gate-phase mapping ----
    const int b = tid & 31, hc = tid >> 5;  // b in [0,32), hc in [0,16)
    const int colg = cu * 16 + hc;
    const float* bias = (l == 0) ? b0 : (bl + (size_t)(l - 1) * 4096);
    const float bi = bias[colg], bf = bias[1024 + colg];
    const float bg = bias[2048 + colg], bo = bias[3072 + colg];
    float c_reg = c0[(size_t)l * 32768 + b * 1024 + colg];

    half_t* houtl = hO + (size_t)l * LSTRIDE;
    const half_t* hin_base = (l == 0) ? xb : (hO + (size_t)(l - 1) * LSTRIDE);

    // A-frag lane offset within a slot: chunk (kq&1)*64 + 2c + (lane>>5), halfs [b][j]
    const size_t aoff = (size_t)((kq & 1) * 64 + (lane >> 5)) * 256 + (size_t)(lane & 31) * 8;

    for (int s = 0; s < NSTAGE; ++s) {
        const int t = s - 3 * l;
        const bool active = (t >= 0 && t < TSEQ);
        const half_t* ap = nullptr;
        f16x8 ar[8];
        if (active && !skipq) {
            const half_t* srcx = (l == 0) ? (xb + (size_t)t * SLOT)
                                          : (hin_base + (size_t)(t + 1) * SLOT);
            const half_t* srch = houtl + (size_t)t * SLOT;
            ap = ((kq < 2) ? srcx : srch) + aoff;
            if (kq < 2) {  // x-part: data ready since stage s-3; prefetch before polling
#pragma unroll
                for (int p = 0; p < 8; ++p) ar[p] = *(const f16x8*)(ap + (size_t)p * 512);
            }
        }
        // ---- flag waits ----
        if (tid < 64) {
            if (s >= 1) {
                const int* fp = &flags[(l * 64 + tid) * 16];
                while (__hip_atomic_load(fp, __ATOMIC_RELAXED, __HIP_MEMORY_SCOPE_AGENT) < s)
                    __builtin_amdgcn_s_sleep(1);
            }
        } else if (tid < 128 && l > 0 && s >= 2) {
            const int* fp = &flags[((l - 1) * 64 + (tid - 64)) * 16];
            while (__hip_atomic_load(fp, __ATOMIC_RELAXED, __HIP_MEMORY_SCOPE_AGENT) < s - 1)
                __builtin_amdgcn_s_sleep(2);
        }
        __syncthreads();  // B1: deps satisfied; zbuf/hbuf WAR protection
        if (active) {
            f32x16 acc;
#pragma unroll
            for (int r = 0; r < 16; ++r) acc[r] = 0.f;
            if (!skipq) {
                if (kq >= 2) {  // h-part: only now guaranteed published
#pragma unroll
                    for (int p = 0; p < 8; ++p) ar[p] = *(const f16x8*)(ap + (size_t)p * 512);
                }
#pragma unroll
                for (int c = 0; c < 32; ++c) {
                    f16x8 a = ar[c & 7];
                    if (c < 24) ar[c & 7] = *(const f16x8*)(ap + (size_t)(c + 8) * 512);
                    acc = __builtin_amdgcn_mfma_f32_32x32x16_f16(a, bfr[c], acc, 0, 0, 0);
                }
            }
            // ---- zbuf (transposed, stride 129: conflict-free write & read) ----
            {
                int col = nt * 32 + (lane & 31);
                float* zc = zbuf + col * 129 + kq * 32 + 4 * (lane >> 5);
#pragma unroll
                for (int r = 0; r < 16; ++r) zc[(r & 3) + 8 * (r >> 2)] = acc[r];
            }
            __syncthreads();  // B2: partials ready
            // ---- gates: thread (b, hc) sums 4 K-quarter partials per gate ----
            {
                float zg4[4];
#pragma unroll
                for (int gi = 0; gi < 4; ++gi) {
                    const float* zc = zbuf + (gi * 16 + hc) * 129 + b;
                    zg4[gi] = (zc[0] + zc[32]) + (zc[64] + zc[96]);
                }
                float zi = zg4[0] + bi, zf = zg4[1] + bf;
                float zg = zg4[2] + bg, zo = zg4[3] + bo;
                c_reg = sigmoidf_(zf) * c_reg + sigmoidf_(zi) * tanhf_(zg);
                float h = sigmoidf_(zo) * tanhf_(c_reg);
                hbuf[(hc >> 3) * 256 + b * 8 + (hc & 7)] = (half_t)h;
            }
            __syncthreads();  // B3: hbuf complete
            // ---- publish h slot t+1 (device-visible stores, 8B each) ----
            if (tid < 128) {
                u64 v = ((const u64*)hbuf)[tid];
                u64* dst = (u64*)(houtl + (size_t)(t + 1) * SLOT) + cu * 128 + tid;
                __hip_atomic_store(dst, v, __ATOMIC_RELAXED, __HIP_MEMORY_SCOPE_AGENT);
            }
        }
        __syncthreads();  // B4: all waves' stores drained before flag post
        if (s < NSTAGE - 1 && tid == 0)
            __hip_atomic_store(&flags[wg * 16], s + 1, __ATOMIC_RELEASE,
                               __HIP_MEMORY_SCOPE_AGENT);
    }
}

// ---- head: out[b][o] = sum_k h_last[b][k] * Wout[k][o] + bout[o] ----
// h_last = hO layer3 slot 512, blocked [k>>3][b][k&7]
__global__ void head_gemm(const half_t* __restrict__ hO, const float* __restrict__ Wout,
                          const float* __restrict__ bout, float* __restrict__ out) {
    int o = blockIdx.x * 32 + (threadIdx.x & 31);
    int b = blockIdx.y * 8 + (threadIdx.x >> 5);
    const half_t* h = hO + (size_t)3 * LSTRIDE + (size_t)512 * SLOT + b * 8;
    float acc = 0.f;
    for (int kb = 0; kb < 128; ++kb) {
        const half_t* hp = h + (size_t)kb * 256;
#pragma unroll
        for (int j = 0; j < 8; ++j)
            acc += (float)hp[j] * Wout[(size_t)(kb * 8 + j) * 1024 + o];
    }
    out[b * 1024 + o] = acc + bout[o];
}

extern "C" void kernel_launch(void* const* d_in, const int* in_sizes, int n_in,
                              void* d_out, int out_size, void* d_ws, size_t ws_size,
                              hipStream_t stream) {
    const float* x    = (const float*)d_in[0];
    const float* h0   = (const float*)d_in[1];
    const float* c0   = (const float*)d_in[2];
    const float* W0   = (const float*)d_in[3];
    const float* b0   = (const float*)d_in[4];
    const float* Wl   = (const float*)d_in[5];
    const float* bl   = (const float*)d_in[6];
    const float* Wout = (const float*)d_in[7];
    const float* bout = (const float*)d_in[8];
    float* out = (float*)d_out;

    char* ws = (char*)d_ws;
    size_t off = 0;
    auto alloc = [&](size_t bytes) {
        size_t r = off;
        off = (off + bytes + 255) & ~(size_t)255;
        return r;
    };
    half_t* WTp = (half_t*)(ws + alloc((size_t)4 * 64 * 131072 * 2));  // 67.1 MB
    half_t* xb  = (half_t*)(ws + alloc((size_t)512 * SLOT * 2));       // 33.6 MB
    half_t* hO  = (half_t*)(ws + alloc((size_t)4 * LSTRIDE * 2));      // 134.5 MB
    int* flags  = (int*)(ws + alloc((size_t)256 * 16 * 4));

    wconv_pack<<<16384, 256, 0, stream>>>(W0, Wl, WTp);
    xconv<<<8192, 256, 0, stream>>>(x, xb);
    hinit<<<64, 256, 0, stream>>>(h0, hO);
    init_flags<<<16, 256, 0, stream>>>(flags, 256 * 16);

    lstm_pipe<<<256, 512, 0, stream>>>(WTp, xb, b0, bl, c0, hO, flags);

    head_gemm<<<dim3(32, 4), 256, 0, stream>>>(hO, Wout, bout, out);
}

// Round 6
// 4366.274 us; speedup vs baseline: 1.0016x; 1.0016x over previous
//
#include <hip/hip_runtime.h>
#include <stdint.h>
#include <stddef.h>

typedef _Float16 half_t;
typedef __attribute__((ext_vector_type(8))) _Float16 f16x8;
typedef __attribute__((ext_vector_type(16))) float f32x16;
typedef unsigned long long u64;

#define TSEQ 512
#define NSTAGE 521            // 512 + 3*3 fill (cross-layer lag-3)
#define SLOT 32768            // halfs per h slot (32 b x 1024 h)
#define LSTRIDE ((size_t)513 * SLOT)

__device__ __forceinline__ float sigmoidf_(float x) { return 1.f / (1.f + __expf(-x)); }
__device__ __forceinline__ float tanhf_(float x) { return 1.f - 2.f / (__expf(2.f * x) + 1.f); }

__device__ __forceinline__ void async_copy16(const void* g, void* l) {
    __builtin_amdgcn_global_load_lds((const __attribute__((address_space(1))) void*)g,
                                     (__attribute__((address_space(3))) void*)l, 16, 0, 0);
}

// ---- pack weights into per-CU, per-wave MFMA B-fragment order, f32 -> f16 ----
// linear half idx = wg*131072 + wid*16384 + c*512 + lane*8   (wid = kq*2+nt)
// n' = nt*32+(lane&31): gate g = n'>>4, hcol = n'&15, n_glob = g*1024+cu*16+hcol
// k = kq*512 + c*16 + (lane>>5)*8 + j
// Layer 0 K-map: k<512 -> W0 row k (x); 512<=k<1024 -> zero; k>=1024 -> W0 row k-512 (h).
__global__ void wconv_pack(const float* __restrict__ W0, const float* __restrict__ Wl,
                           half_t* __restrict__ WTp) {
    int idx = blockIdx.x * 256 + threadIdx.x;  // 0 .. 2^22-1
    int lane = idx & 63, c = (idx >> 6) & 31, nt = (idx >> 11) & 1;
    int kq = (idx >> 12) & 3, cu = (idx >> 14) & 63, l = idx >> 20;
    int np = nt * 32 + (lane & 31);
    int n = (np >> 4) * 1024 + cu * 16 + (np & 15);
    int kbase = kq * 512 + c * 16 + (lane >> 5) * 8;
    half_t tmp[8];
#pragma unroll
    for (int j = 0; j < 8; ++j) {
        int k = kbase + j;
        float v;
        if (l == 0) {
            if (k < 512) v = W0[(size_t)k * 4096 + n];
            else if (k < 1024) v = 0.f;
            else v = W0[(size_t)(k - 512) * 4096 + n];
        } else {
            v = Wl[((size_t)(l - 1) * 2048 + k) * 4096 + n];
        }
        tmp[j] = (half_t)v;
    }
    *(int4*)(WTp + (size_t)idx * 8) = *(int4*)tmp;
}

// ---- x f32 [32 b][512 t][512 k] -> xb f16 [t][128 c][32 b][8 j], zeros for c>=64 ----
__global__ void xconv(const float* __restrict__ x, half_t* __restrict__ xb) {
    int idx = blockIdx.x * 256 + threadIdx.x;  // 0 .. 2^21-1
    int b = idx & 31, c = (idx >> 5) & 127, t = idx >> 12;
    half_t tmp[8];
#pragma unroll
    for (int j = 0; j < 8; ++j)
        tmp[j] = (c < 64) ? (half_t)x[((size_t)b * 512 + t) * 512 + c * 8 + j] : (half_t)0.f;
    *(int4*)(xb + (size_t)idx * 8) = *(int4*)tmp;
}

// ---- h0 f32 [l][32 b][1024] -> h_out[l] slot 0 blocked [c][b][j] ----
__global__ void hinit(const float* __restrict__ h0, half_t* __restrict__ hO) {
    int idx = blockIdx.x * 256 + threadIdx.x;  // 0..16383
    int b = idx & 31, c = (idx >> 5) & 127, l = idx >> 12;
    half_t tmp[8];
#pragma unroll
    for (int j = 0; j < 8; ++j) tmp[j] = (half_t)h0[(size_t)l * 32768 + b * 1024 + c * 8 + j];
    *(int4*)(hO + (size_t)l * LSTRIDE + (size_t)(c * 32 + b) * 8) = *(int4*)tmp;
}

__global__ void init_flags(int* f, int n) {
    int i = blockIdx.x * blockDim.x + threadIdx.x;
    if (i < n) f[i] = 0;
}

// ---- persistent pipelined LSTM: 256 WGs (1/CU) x 512 threads (8 waves) ----
// WG wg: layer l = wg>>6, cu = wg&63 owns h-cols [cu*16, cu*16+16) of layer l.
// Wave wid: kq = wid>>1 (K quarter of 512), nt = wid&1 (32-col half of the 64 z-cols).
// SPLIT-LAG schedule: stage s, layer l computes t = s - 3l (intra-layer lag-1 tight wait,
// cross-layer lag-3 -> x-part prefetch before polling; see R5 notes).
// R6: weights are staged global->LDS->VGPR at startup, then zbuf ALIASES the weight LDS.
// This makes rematerialization of the B-fragments impossible -> true register residency.
__global__ void __launch_bounds__(512, 2) lstm_pipe(
        const half_t* __restrict__ WTp, const half_t* __restrict__ xb,
        const float* __restrict__ b0, const float* __restrict__ bl,
        const float* __restrict__ c0, half_t* __restrict__ hO,
        int* __restrict__ flags) {
    __shared__ char smem[132096];              // 128K weight-staging region + 1K hbuf
    float* zbuf = (float*)smem;                // alias: [col 64][row 128+1 pad] f32 = 33 KB
    half_t* hbuf = (half_t*)(smem + 131072);   // [512] halfs

    const int tid = threadIdx.x;
    const int wg = blockIdx.x;
    const int l = wg >> 6, cu = wg & 63;
    const int lane = tid & 63, wid = tid >> 6;
    const int kq = wid >> 1, nt = wid & 1;
    const bool skipq = (l == 0 && kq == 1);  // zero-padded K region of layer 0

    // ---- stage weights (256 KB/WG) into LDS in two 128 KB halves, then into VGPRs ----
    f16x8 bfr[32];
    {
        const char* wgw = (const char*)(WTp + (size_t)wg * 131072);
#pragma unroll
        for (int it = 0; it < 16; ++it)
            async_copy16(wgw + it * 8192 + tid * 16, smem + it * 8192 + tid * 16);
        __syncthreads();
        if (wid < 4) {
#pragma unroll
            for (int c = 0; c < 32; ++c)
                bfr[c] = *(const f16x8*)(smem + (wid * 32 + c) * 1024 + lane * 16);
        }
        __syncthreads();
#pragma unroll
        for (int it = 0; it < 16; ++it)
            async_copy16(wgw + 131072 + it * 8192 + tid * 16, smem + it * 8192 + tid * 16);
        __syncthreads();
        if (wid >= 4) {
#pragma unroll
            for (int c = 0; c < 32; ++c)
                bfr[c] = *(const f16x8*)(smem + ((wid - 4) * 32 + c) * 1024 + lane * 16);
        }
        __syncthreads();
    }

    // ---- gate-phase mapping ----
    const int b = tid & 31, hc = tid >> 5;  // b in [0,32), hc in [0,16)
    const int colg = cu * 16 + hc;
    const float* bias = (l == 0) ? b0 : (bl + (size_t)(l - 1) * 4096);
    const float bi = bias[colg], bf = bias[1024 + colg];
    const float bg = bias[2048 + colg], bo = bias[3072 + colg];
    float c_reg = c0[(size_t)l * 32768 + b * 1024 + colg];

    half_t* houtl = hO + (size_t)l * LSTRIDE;
    const half_t* hin_base = (l == 0) ? xb : (hO + (size_t)(l - 1) * LSTRIDE);

    // A-frag lane offset within a slot: chunk (kq&1)*64 + 2c + (lane>>5), halfs [b][j]
    const size_t aoff = (size_t)((kq & 1) * 64 + (lane >> 5)) * 256 + (size_t)(lane & 31) * 8;

    for (int s = 0; s < NSTAGE; ++s) {
        const int t = s - 3 * l;
        const bool active = (t >= 0 && t < TSEQ);
        const half_t* ap = nullptr;
        f16x8 ar[8];
        if (active && !skipq) {
            const half_t* srcx = (l == 0) ? (xb + (size_t)t * SLOT)
                                          : (hin_base + (size_t)(t + 1) * SLOT);
            const half_t* srch = houtl + (size_t)t * SLOT;
            ap = ((kq < 2) ? srcx : srch) + aoff;
            if (kq < 2) {  // x-part: data ready since stage s-3; prefetch before polling
#pragma unroll
                for (int p = 0; p < 8; ++p) ar[p] = *(const f16x8*)(ap + (size_t)p * 512);
            }
        }
        // ---- flag waits ----
        if (tid < 64) {
            if (s >= 1) {
                const int* fp = &flags[(l * 64 + tid) * 16];
                while (__hip_atomic_load(fp, __ATOMIC_RELAXED, __HIP_MEMORY_SCOPE_AGENT) < s)
                    __builtin_amdgcn_s_sleep(1);
            }
        } else if (tid < 128 && l > 0 && s >= 2) {
            const int* fp = &flags[((l - 1) * 64 + (tid - 64)) * 16];
            while (__hip_atomic_load(fp, __ATOMIC_RELAXED, __HIP_MEMORY_SCOPE_AGENT) < s - 1)
                __builtin_amdgcn_s_sleep(2);
        }
        __syncthreads();  // B1: deps satisfied
        if (active) {
            f32x16 acc;
#pragma unroll
            for (int r = 0; r < 16; ++r) acc[r] = 0.f;
            if (!skipq) {
                if (kq >= 2) {  // h-part: only now guaranteed published
#pragma unroll
                    for (int p = 0; p < 8; ++p) ar[p] = *(const f16x8*)(ap + (size_t)p * 512);
                }
#pragma unroll
                for (int c = 0; c < 32; ++c) {
                    f16x8 a = ar[c & 7];
                    if (c < 24) ar[c & 7] = *(const f16x8*)(ap + (size_t)(c + 8) * 512);
                    acc = __builtin_amdgcn_mfma_f32_32x32x16_f16(a, bfr[c], acc, 0, 0, 0);
                }
            }
            // ---- zbuf (transposed, stride 129: conflict-free write & read) ----
            {
                int col = nt * 32 + (lane & 31);
                float* zc = zbuf + col * 129 + kq * 32 + 4 * (lane >> 5);
#pragma unroll
                for (int r = 0; r < 16; ++r) zc[(r & 3) + 8 * (r >> 2)] = acc[r];
            }
            __syncthreads();  // B2: partials ready
            // ---- gates: thread (b, hc) sums 4 K-quarter partials per gate ----
            {
                float zg4[4];
#pragma unroll
                for (int gi = 0; gi < 4; ++gi) {
                    const float* zc = zbuf + (gi * 16 + hc) * 129 + b;
                    zg4[gi] = (zc[0] + zc[32]) + (zc[64] + zc[96]);
                }
                float zi = zg4[0] + bi, zf = zg4[1] + bf;
                float zg = zg4[2] + bg, zo = zg4[3] + bo;
                c_reg = sigmoidf_(zf) * c_reg + sigmoidf_(zi) * tanhf_(zg);
                float h = sigmoidf_(zo) * tanhf_(c_reg);
                hbuf[(hc >> 3) * 256 + b * 8 + (hc & 7)] = (half_t)h;
            }
            __syncthreads();  // B3: hbuf complete
            // ---- publish h slot t+1 (device-visible stores, 8B each) ----
            if (tid < 128) {
                u64 v = ((const u64*)hbuf)[tid];
                u64* dst = (u64*)(houtl + (size_t)(t + 1) * SLOT) + cu * 128 + tid;
                __hip_atomic_store(dst, v, __ATOMIC_RELAXED, __HIP_MEMORY_SCOPE_AGENT);
            }
        }
        __syncthreads();  // B4: all waves' stores drained before flag post
        if (s < NSTAGE - 1 && tid == 0)
            __hip_atomic_store(&flags[wg * 16], s + 1, __ATOMIC_RELEASE,
                               __HIP_MEMORY_SCOPE_AGENT);
    }
}

// ---- head: out[b][o] = sum_k h_last[b][k] * Wout[k][o] + bout[o] ----
// h_last = hO layer3 slot 512, blocked [k>>3][b][k&7]
__global__ void head_gemm(const half_t* __restrict__ hO, const float* __restrict__ Wout,
                          const float* __restrict__ bout, float* __restrict__ out) {
    int o = blockIdx.x * 32 + (threadIdx.x & 31);
    int b = blockIdx.y * 8 + (threadIdx.x >> 5);
    const half_t* h = hO + (size_t)3 * LSTRIDE + (size_t)512 * SLOT + b * 8;
    float acc = 0.f;
    for (int kb = 0; kb < 128; ++kb) {
        const half_t* hp = h + (size_t)kb * 256;
#pragma unroll
        for (int j = 0; j < 8; ++j)
            acc += (float)hp[j] * Wout[(size_t)(kb * 8 + j) * 1024 + o];
    }
    out[b * 1024 + o] = acc + bout[o];
}

extern "C" void kernel_launch(void* const* d_in, const int* in_sizes, int n_in,
                              void* d_out, int out_size, void* d_ws, size_t ws_size,
                              hipStream_t stream) {
    const float* x    = (const float*)d_in[0];
    const float* h0   = (const float*)d_in[1];
    const float* c0   = (const float*)d_in[2];
    const float* W0   = (const float*)d_in[3];
    const float* b0   = (const float*)d_in[4];
    const float* Wl   = (const float*)d_in[5];
    const float* bl   = (const float*)d_in[6];
    const float* Wout = (const float*)d_in[7];
    const float* bout = (const float*)d_in[8];
    float* out = (float*)d_out;

    char* ws = (char*)d_ws;
    size_t off = 0;
    auto alloc = [&](size_t bytes) {
        size_t r = off;
        off = (off + bytes + 255) & ~(size_t)255;
        return r;
    };
    half_t* WTp = (half_t*)(ws + alloc((size_t)4 * 64 * 131072 * 2));  // 67.1 MB
    half_t* xb  = (half_t*)(ws + alloc((size_t)512 * SLOT * 2));       // 33.6 MB
    half_t* hO  = (half_t*)(ws + alloc((size_t)4 * LSTRIDE * 2));      // 134.5 MB
    int* flags  = (int*)(ws + alloc((size_t)256 * 16 * 4));

    wconv_pack<<<16384, 256, 0, stream>>>(W0, Wl, WTp);
    xconv<<<8192, 256, 0, stream>>>(x, xb);
    hinit<<<64, 256, 0, stream>>>(h0, hO);
    init_flags<<<16, 256, 0, stream>>>(flags, 256 * 16);

    lstm_pipe<<<256, 512, 0, stream>>>(WTp, xb, b0, bl, c0, hO, flags);

    head_gemm<<<dim3(32, 4), 256, 0, stream>>>(hO, Wout, bout, out);
}

// Round 8
// 3446.684 us; speedup vs baseline: 1.2688x; 1.2668x over previous
//
#include <hip/hip_runtime.h>
#include <stdint.h>
#include <stddef.h>

typedef _Float16 half_t;
typedef __attribute__((ext_vector_type(8))) _Float16 f16x8;
typedef __attribute__((ext_vector_type(16))) float f32x16;
typedef unsigned long long u64;

#define TSEQ 512
#define NSTAGE 521            // 512 + 3*3 fill (cross-layer lag-3)
#define SLOT 32768            // halfs per h slot (32 b x 1024 h)
#define LSTRIDE ((size_t)513 * SLOT)

__device__ __forceinline__ float sigmoidf_(float x) { return 1.f / (1.f + __expf(-x)); }
__device__ __forceinline__ float tanhf_(float x) { return 1.f - 2.f / (__expf(2.f * x) + 1.f); }

__device__ __forceinline__ void async_copy16(const void* g, void* l) {
    __builtin_amdgcn_global_load_lds((const __attribute__((address_space(1))) void*)g,
                                     (__attribute__((address_space(3))) void*)l, 16, 0, 0);
}

// ---- pack weights into per-CU, per-wave MFMA B-fragment order, f32 -> f16 ----
// linear half idx = wg*131072 + wid*16384 + c*512 + lane*8   (wid = kq*2+nt)
// n' = nt*32+(lane&31): gate g = n'>>4, hcol = n'&15, n_glob = g*1024+cu*16+hcol
// k = kq*512 + c*16 + (lane>>5)*8 + j
// Layer 0 K-map: k<512 -> W0 row k (x); 512<=k<1024 -> zero; k>=1024 -> W0 row k-512 (h).
__global__ void wconv_pack(const float* __restrict__ W0, const float* __restrict__ Wl,
                           half_t* __restrict__ WTp) {
    int idx = blockIdx.x * 256 + threadIdx.x;  // 0 .. 2^22-1
    int lane = idx & 63, c = (idx >> 6) & 31, nt = (idx >> 11) & 1;
    int kq = (idx >> 12) & 3, cu = (idx >> 14) & 63, l = idx >> 20;
    int np = nt * 32 + (lane & 31);
    int n = (np >> 4) * 1024 + cu * 16 + (np & 15);
    int kbase = kq * 512 + c * 16 + (lane >> 5) * 8;
    half_t tmp[8];
#pragma unroll
    for (int j = 0; j < 8; ++j) {
        int k = kbase + j;
        float v;
        if (l == 0) {
            if (k < 512) v = W0[(size_t)k * 4096 + n];
            else if (k < 1024) v = 0.f;
            else v = W0[(size_t)(k - 512) * 4096 + n];
        } else {
            v = Wl[((size_t)(l - 1) * 2048 + k) * 4096 + n];
        }
        tmp[j] = (half_t)v;
    }
    *(int4*)(WTp + (size_t)idx * 8) = *(int4*)tmp;
}

// ---- x f32 [32 b][512 t][512 k] -> xb f16 [t][128 c][32 b][8 j], zeros for c>=64 ----
__global__ void xconv(const float* __restrict__ x, half_t* __restrict__ xb) {
    int idx = blockIdx.x * 256 + threadIdx.x;  // 0 .. 2^21-1
    int b = idx & 31, c = (idx >> 5) & 127, t = idx >> 12;
    half_t tmp[8];
#pragma unroll
    for (int j = 0; j < 8; ++j)
        tmp[j] = (c < 64) ? (half_t)x[((size_t)b * 512 + t) * 512 + c * 8 + j] : (half_t)0.f;
    *(int4*)(xb + (size_t)idx * 8) = *(int4*)tmp;
}

// ---- h0 f32 [l][32 b][1024] -> h_out[l] slot 0 blocked [c][b][j] ----
__global__ void hinit(const float* __restrict__ h0, half_t* __restrict__ hO) {
    int idx = blockIdx.x * 256 + threadIdx.x;  // 0..16383
    int b = idx & 31, c = (idx >> 5) & 127, l = idx >> 12;
    half_t tmp[8];
#pragma unroll
    for (int j = 0; j < 8; ++j) tmp[j] = (half_t)h0[(size_t)l * 32768 + b * 1024 + c * 8 + j];
    *(int4*)(hO + (size_t)l * LSTRIDE + (size_t)(c * 32 + b) * 8) = *(int4*)tmp;
}

__global__ void init_flags(int* f, int n) {
    int i = blockIdx.x * blockDim.x + threadIdx.x;
    if (i < n) f[i] = 0;
}

// ---- persistent pipelined LSTM: 256 WGs (1/CU) x 512 threads (8 waves) ----
// WG wg: layer l = wg>>6, cu = wg&63 owns h-cols [cu*16, cu*16+16) of layer l.
// Wave wid: kq = wid>>1 (K quarter of 512), nt = wid&1 (32-col half of the 64 z-cols).
// SPLIT-LAG schedule: stage s, layer l computes t = s - 3l (intra-layer lag-1 tight,
// cross-layer lag-3 -> x-part loads issued BEFORE polling; induction per R5 notes).
// R8: FULL 32-fragment A prefetch in VGPRs. x-waves load pre-poll (complete under the
// poll); h-waves load post-B1 with all 32 in flight (one exposed latency, not 4 rounds).
// Flag post RELAXED: B4's vmcnt(0) barrier drain orders the sc1 publishes before it.
__global__ void __launch_bounds__(512, 2) lstm_pipe(
        const half_t* __restrict__ WTp, const half_t* __restrict__ xb,
        const float* __restrict__ b0, const float* __restrict__ bl,
        const float* __restrict__ c0, half_t* __restrict__ hO,
        int* __restrict__ flags) {
    __shared__ char smem[132096];              // init: 128K weight staging; steady: zbuf+hbuf
    float* zbuf = (float*)smem;                // alias: [col 64][row 128+1 pad] f32 = 33 KB
    half_t* hbuf = (half_t*)(smem + 131072);   // [512] halfs

    const int tid = threadIdx.x;
    const int wg = blockIdx.x;
    const int l = wg >> 6, cu = wg & 63;
    const int lane = tid & 63, wid = tid >> 6;
    const int kq = wid >> 1, nt = wid & 1;
    const bool skipq = (l == 0 && kq == 1);  // zero-padded K region of layer 0

    // ---- stage weights (256 KB/WG) into LDS in two 128 KB halves, then into regs ----
    f16x8 bfr[32];
    {
        const char* wgw = (const char*)(WTp + (size_t)wg * 131072);
#pragma unroll
        for (int it = 0; it < 16; ++it)
            async_copy16(wgw + it * 8192 + tid * 16, smem + it * 8192 + tid * 16);
        __syncthreads();
        if (wid < 4) {
#pragma unroll
            for (int c = 0; c < 32; ++c)
                bfr[c] = *(const f16x8*)(smem + (wid * 32 + c) * 1024 + lane * 16);
        }
        __syncthreads();
#pragma unroll
        for (int it = 0; it < 16; ++it)
            async_copy16(wgw + 131072 + it * 8192 + tid * 16, smem + it * 8192 + tid * 16);
        __syncthreads();
        if (wid >= 4) {
#pragma unroll
            for (int c = 0; c < 32; ++c)
                bfr[c] = *(const f16x8*)(smem + ((wid - 4) * 32 + c) * 1024 + lane * 16);
        }
        __syncthreads();
    }

    // ---- gate-phase mapping ----
    const int b = tid & 31, hc = tid >> 5;  // b in [0,32), hc in [0,16)
    const int colg = cu * 16 + hc;
    const float* bias = (l == 0) ? b0 : (bl + (size_t)(l - 1) * 4096);
    const float bi = bias[colg], bf = bias[1024 + colg];
    const float bg = bias[2048 + colg], bo = bias[3072 + colg];
    float c_reg = c0[(size_t)l * 32768 + b * 1024 + colg];

    half_t* houtl = hO + (size_t)l * LSTRIDE;
    const half_t* hin_base = (l == 0) ? xb : (hO + (size_t)(l - 1) * LSTRIDE);

    // A-frag lane offset within a slot: chunk (kq&1)*64 + 2c + (lane>>5), halfs [b][j]
    const size_t aoff = (size_t)((kq & 1) * 64 + (lane >> 5)) * 256 + (size_t)(lane & 31) * 8;

    for (int s = 0; s < NSTAGE; ++s) {
        const int t = s - 3 * l;
        const bool active = (t >= 0 && t < TSEQ);
        const half_t* ap = nullptr;
        f16x8 ar[32];
        if (active && !skipq) {
            const half_t* srcx = (l == 0) ? (xb + (size_t)t * SLOT)
                                          : (hin_base + (size_t)(t + 1) * SLOT);
            const half_t* srch = houtl + (size_t)t * SLOT;
            ap = ((kq < 2) ? srcx : srch) + aoff;
            if (kq < 2) {  // x-part: published since stage s-3; all 32 in flight pre-poll
#pragma unroll
                for (int p = 0; p < 32; ++p) ar[p] = *(const f16x8*)(ap + (size_t)p * 512);
            }
        }
        // ---- flag waits ----
        if (tid < 64) {
            if (s >= 1) {
                const int* fp = &flags[(l * 64 + tid) * 16];
                while (__hip_atomic_load(fp, __ATOMIC_RELAXED, __HIP_MEMORY_SCOPE_AGENT) < s)
                    __builtin_amdgcn_s_sleep(1);
            }
        } else if (tid < 128 && l > 0 && s >= 2) {
            const int* fp = &flags[((l - 1) * 64 + (tid - 64)) * 16];
            while (__hip_atomic_load(fp, __ATOMIC_RELAXED, __HIP_MEMORY_SCOPE_AGENT) < s - 1)
                __builtin_amdgcn_s_sleep(2);
        }
        __syncthreads();  // B1: deps satisfied
        if (active) {
            f32x16 acc;
#pragma unroll
            for (int r = 0; r < 16; ++r) acc[r] = 0.f;
            if (!skipq) {
                if (kq >= 2) {  // h-part: now guaranteed published; all 32 in flight at once
#pragma unroll
                    for (int p = 0; p < 32; ++p) ar[p] = *(const f16x8*)(ap + (size_t)p * 512);
                }
#pragma unroll
                for (int c = 0; c < 32; ++c)
                    acc = __builtin_amdgcn_mfma_f32_32x32x16_f16(ar[c], bfr[c], acc, 0, 0, 0);
            }
            // ---- zbuf (transposed, stride 129: conflict-free write & read) ----
            {
                int col = nt * 32 + (lane & 31);
                float* zc = zbuf + col * 129 + kq * 32 + 4 * (lane >> 5);
#pragma unroll
                for (int r = 0; r < 16; ++r) zc[(r & 3) + 8 * (r >> 2)] = acc[r];
            }
            __syncthreads();  // B2: partials ready
            // ---- gates: thread (b, hc) sums 4 K-quarter partials per gate ----
            {
                float zg4[4];
#pragma unroll
                for (int gi = 0; gi < 4; ++gi) {
                    const float* zc = zbuf + (gi * 16 + hc) * 129 + b;
                    zg4[gi] = (zc[0] + zc[32]) + (zc[64] + zc[96]);
                }
                float zi = zg4[0] + bi, zf = zg4[1] + bf;
                float zg = zg4[2] + bg, zo = zg4[3] + bo;
                c_reg = sigmoidf_(zf) * c_reg + sigmoidf_(zi) * tanhf_(zg);
                float h = sigmoidf_(zo) * tanhf_(c_reg);
                hbuf[(hc >> 3) * 256 + b * 8 + (hc & 7)] = (half_t)h;
            }
            __syncthreads();  // B3: hbuf complete
            // ---- publish h slot t+1 (sc1 device-visible stores, 8B each) ----
            if (tid < 128) {
                u64 v = ((const u64*)hbuf)[tid];
                u64* dst = (u64*)(houtl + (size_t)(t + 1) * SLOT) + cu * 128 + tid;
                __hip_atomic_store(dst, v, __ATOMIC_RELAXED, __HIP_MEMORY_SCOPE_AGENT);
            }
        }
        __syncthreads();  // B4: all waves drained (vmcnt 0) -> publishes ordered before post
        if (s < NSTAGE - 1 && tid == 0)
            __hip_atomic_store(&flags[wg * 16], s + 1, __ATOMIC_RELAXED,
                               __HIP_MEMORY_SCOPE_AGENT);
    }
}

// ---- head: out[b][o] = sum_k h_last[b][k] * Wout[k][o] + bout[o] ----
// h_last = hO layer3 slot 512, blocked [k>>3][b][k&7]
__global__ void head_gemm(const half_t* __restrict__ hO, const float* __restrict__ Wout,
                          const float* __restrict__ bout, float* __restrict__ out) {
    int o = blockIdx.x * 32 + (threadIdx.x & 31);
    int b = blockIdx.y * 8 + (threadIdx.x >> 5);
    const half_t* h = hO + (size_t)3 * LSTRIDE + (size_t)512 * SLOT + b * 8;
    float acc = 0.f;
    for (int kb = 0; kb < 128; ++kb) {
        const half_t* hp = h + (size_t)kb * 256;
#pragma unroll
        for (int j = 0; j < 8; ++j)
            acc += (float)hp[j] * Wout[(size_t)(kb * 8 + j) * 1024 + o];
    }
    out[b * 1024 + o] = acc + bout[o];
}

extern "C" void kernel_launch(void* const* d_in, const int* in_sizes, int n_in,
                              void* d_out, int out_size, void* d_ws, size_t ws_size,
                              hipStream_t stream) {
    const float* x    = (const float*)d_in[0];
    const float* h0   = (const float*)d_in[1];
    const float* c0   = (const float*)d_in[2];
    const float* W0   = (const float*)d_in[3];
    const float* b0   = (const float*)d_in[4];
    const float* Wl   = (const float*)d_in[5];
    const float* bl   = (const float*)d_in[6];
    const float* Wout = (const float*)d_in[7];
    const float* bout = (const float*)d_in[8];
    float* out = (float*)d_out;

    char* ws = (char*)d_ws;
    size_t off = 0;
    auto alloc = [&](size_t bytes) {
        size_t r = off;
        off = (off + bytes + 255) & ~(size_t)255;
        return r;
    };
    half_t* WTp = (half_t*)(ws + alloc((size_t)4 * 64 * 131072 * 2));  // 67.1 MB
    half_t* xb  = (half_t*)(ws + alloc((size_t)512 * SLOT * 2));       // 33.6 MB
    half_t* hO  = (half_t*)(ws + alloc((size_t)4 * LSTRIDE * 2));      // 134.5 MB
    int* flags  = (int*)(ws + alloc((size_t)256 * 16 * 4));

    wconv_pack<<<16384, 256, 0, stream>>>(W0, Wl, WTp);
    xconv<<<8192, 256, 0, stream>>>(x, xb);
    hinit<<<64, 256, 0, stream>>>(h0, hO);
    init_flags<<<16, 256, 0, stream>>>(flags, 256 * 16);

    lstm_pipe<<<256, 512, 0, stream>>>(WTp, xb, b0, bl, c0, hO, flags);

    head_gemm<<<dim3(32, 4), 256, 0, stream>>>(hO, Wout, bout, out);
}